// Round 2
// baseline (361.544 us; speedup 1.0000x reference)
//
#include <hip/hip_runtime.h>
#include <hip/hip_bf16.h>
#include <math.h>

typedef __hip_bfloat16 bf16;
typedef __bf16 v8bf __attribute__((ext_vector_type(8)));
typedef float v4f __attribute__((ext_vector_type(4)));

#define BN_SCALE 0.9999950000374997f
#define NPTS 1024
#define NB 4
#define TW 40  // LDS tile row stride in bf16 (80B: 2-way bank alias only = free)

__device__ __forceinline__ float b2f(bf16 v) { return __bfloat162float(v); }
__device__ __forceinline__ bf16 f2b(float v) { return __float2bfloat16(v); }
__device__ __forceinline__ float ldw(const void* p, size_t i, int isf) {
    return isf ? ((const float*)p)[i] : b2f(((const bf16*)p)[i]);
}
__device__ __forceinline__ unsigned ordf(float f) {
    unsigned u = __float_as_uint(f);
    return (u & 0x80000000u) ? ~u : (u | 0x80000000u);
}
__device__ __forceinline__ float iordf(unsigned u) {
    return (u & 0x80000000u) ? __uint_as_float(u ^ 0x80000000u) : __uint_as_float(~u);
}

// per-block dtype detect from first 512 shorts of x (fp32 ~113/256 implausible, bf16 ~0)
__device__ __forceinline__ int detect_isf(const void* xraw, int* cnt) {
    const unsigned short* u = (const unsigned short*)xraw;
    int t = threadIdx.x, c = 0;
    for (int i = t; i < 512; i += 256) {
        unsigned short v = u[i];
        int e = (v >> 7) & 0xFF;
        int m = v & 0x7F;
        if (e == 0xFF || e >= 141 || (e == 0 && m != 0)) c++;
    }
    cnt[t] = c;
    __syncthreads();
    for (int off = 128; off > 0; off >>= 1) {
        if (t < off) cnt[t] += cnt[t + off];
        __syncthreads();
    }
    int isf = (cnt[0] > 30) ? 1 : 0;
    __syncthreads();
    return isf;
}

// ---------------- fused prep: dtype flag + pooled init + weight splits + x pad + sq ----------------
__global__ void k_prep(const void* __restrict__ W1, const void* __restrict__ W2,
                       const void* __restrict__ W3, const void* __restrict__ W4,
                       const void* __restrict__ W5, const void* __restrict__ x,
                       bf16* __restrict__ Whi, bf16* __restrict__ Wlo,
                       bf16* __restrict__ xph, bf16* __restrict__ xpl, float* __restrict__ sq,
                       int* __restrict__ flag, unsigned* __restrict__ pooledU) {
    __shared__ int cnt[256];
    int isf = detect_isf(x, cnt);
    if (blockIdx.x == 0) {
        if (threadIdx.x == 0) *flag = isf;
        for (int i = threadIdx.x; i < 2048; i += 256) pooledU[i] = 0u;  // 0 < ordf(any finite)
    }
    int idx = blockIdx.x * 256 + threadIdx.x;
    if (idx < 839680) {
        const void* src; int C, O, Kpad, two, local;
        if (idx < 4096)        { src = W1; C = 3;   O = 64;  Kpad = 32;  two = 1; local = idx; }
        else if (idx < 20480)  { src = W2; C = 64;  O = 128; Kpad = 64;  two = 1; local = idx - 4096; }
        else if (idx < 86016)  { src = W3; C = 128; O = 256; Kpad = 128; two = 1; local = idx - 20480; }
        else if (idx < 348160) { src = W4; C = 256; O = 512; Kpad = 256; two = 1; local = idx - 86016; }
        else                   { src = W5; C = 960; O = 512; Kpad = 960; two = 0; local = idx - 348160; }
        int r = local / Kpad, c = local % Kpad;
        float wv = 0.f;
        if (c < C) {
            size_t off;
            if (two) off = (r < O) ? (size_t)r * 2 * C + c : (size_t)(r - O) * 2 * C + C + c;
            else     off = (size_t)r * C + c;
            wv = ldw(src, off, isf);
        }
        bf16 h = f2b(wv);
        Whi[idx] = h;
        Wlo[idx] = f2b(wv - b2f(h));
    } else if (idx < 843776) {
        int p = idx - 839680;       // point index: z*1024 + n
        int z = p >> 10, n = p & 1023;
        bf16* ph = xph + (size_t)z * NPTS * 32;
        bf16* pl = xpl + (size_t)z * NPTS * 32;
        float s = 0.f;
        for (int c = 0; c < 32; c++) {
            float v = (c < 3) ? ldw(x, (size_t)z * NPTS * 3 + n * 3 + c, isf) : 0.f;
            bf16 h = f2b(v);
            ph[n * 32 + c] = h;
            pl[n * 32 + c] = f2b(v - b2f(h));
            s += v * v;
        }
        sq[z * NPTS + n] = s;
    }
}

// fill a 128x32 bf16 tile (rows stride ld) into LDS [128][TW]; 256 threads x 2 x 16B
__device__ __forceinline__ void fill128(bf16* dst, const bf16* src, int ld) {
    int t = threadIdx.x;
    int r = t >> 2, kq = (t & 3) << 3;
    *(float4*)(dst + r * TW + kq) = *(const float4*)(src + (size_t)r * ld + kq);
    *(float4*)(dst + (r + 64) * TW + kq) = *(const float4*)(src + (size_t)(r + 64) * ld + kq);
}
// MFMA fragment: sub-tile 'sub' (16 rows of the 128-row tile), lane l: row=sub*16+(l&15), k=(l>>4)*8
__device__ __forceinline__ v8bf ldf(const bf16* tile, int sub, int l) {
    return *(const v8bf*)(tile + (size_t)(sub * 16 + (l & 15)) * TW + ((l >> 4) << 3));
}

// ---------------- fused layer stage A: dist (upper-tri 128x128 tiles) + st ----------------
// 1D grid, XCD-pinned: z = (i>>1)&3, bi = ((i>>3)<<1)|(i&1)  (batch z -> XCDs {2z,2z+1})
// 128x128 output tile, 4 waves in 2x2, each wave 64x64 (acc[4][4]) -> 48 MFMA : 16 ds_read per K-step
__global__ __launch_bounds__(256) void k_layer_a(const bf16* __restrict__ Xhi, const bf16* __restrict__ Xlo,
                                                 int ld, int Kpad, size_t xstride,
                                                 const bf16* __restrict__ Whi, const bf16* __restrict__ Wlo,
                                                 int O, const float* __restrict__ sqg,
                                                 float* __restrict__ Dg, float* __restrict__ Pg,
                                                 const int* __restrict__ flag) {
    int i = blockIdx.x;
    int z = (i >> 1) & 3;
    int bi = ((i >> 3) << 1) | (i & 1);
    const bf16* Xh = Xhi + (size_t)z * xstride;
    const bf16* Xl = Xlo + (size_t)z * xstride;
    __shared__ alignas(16) bf16 Ah[128 * TW], Al[128 * TW], Bh[128 * TW], Bl[128 * TW];
    int w = threadIdx.x >> 6, l = threadIdx.x & 63;
    int wr = w >> 1, wc = w & 1;
    int quad = l >> 4, col = l & 15;
    v4f zero = {0.f, 0.f, 0.f, 0.f};
    v4f acc[4][4] = {{zero, zero, zero, zero}, {zero, zero, zero, zero},
                     {zero, zero, zero, zero}, {zero, zero, zero, zero}};

    if (bi < 36) {
        // ---- dist tile: triangular decode over 8x8, bx >= by ----
        int bx = 0;
        while ((((bx + 1) * (bx + 2)) >> 1) <= bi) bx++;
        int by = bi - ((bx * (bx + 1)) >> 1);
        const float* sq = sqg + z * NPTS;
        float* D = Dg + (size_t)z * NPTS * NPTS;
        int n0 = by * 128, m0 = bx * 128;
        for (int k0 = 0; k0 < Kpad; k0 += 32) {
            __syncthreads();
            fill128(Ah, Xh + (size_t)n0 * ld + k0, ld);
            fill128(Bh, Xh + (size_t)m0 * ld + k0, ld);
            fill128(Al, Xl + (size_t)n0 * ld + k0, ld);
            fill128(Bl, Xl + (size_t)m0 * ld + k0, ld);
            __syncthreads();
            v8bf ah[4], al[4];
#pragma unroll
            for (int mi = 0; mi < 4; mi++) {
                ah[mi] = ldf(Ah, wr * 4 + mi, l);
                al[mi] = ldf(Al, wr * 4 + mi, l);
            }
#pragma unroll
            for (int ni = 0; ni < 4; ni++) {
                v8bf bh = ldf(Bh, wc * 4 + ni, l);
                v8bf bl = ldf(Bl, wc * 4 + ni, l);
#pragma unroll
                for (int mi = 0; mi < 4; mi++) {
                    acc[mi][ni] = __builtin_amdgcn_mfma_f32_16x16x32_bf16(ah[mi], bh, acc[mi][ni], 0, 0, 0);
                    acc[mi][ni] = __builtin_amdgcn_mfma_f32_16x16x32_bf16(ah[mi], bl, acc[mi][ni], 0, 0, 0);
                    acc[mi][ni] = __builtin_amdgcn_mfma_f32_16x16x32_bf16(al[mi], bh, acc[mi][ni], 0, 0, 0);
                }
            }
        }
        int rb = n0 + wr * 64 + quad * 4;
        int cb = m0 + wc * 64 + col;
        float sm[4];
#pragma unroll
        for (int ni = 0; ni < 4; ni++) sm[ni] = sq[cb + ni * 16];
#pragma unroll
        for (int mi = 0; mi < 4; mi++) {
#pragma unroll
            for (int r = 0; r < 4; r++) {
                int row = rb + mi * 16 + r;
                float sn = sq[row];
#pragma unroll
                for (int ni = 0; ni < 4; ni++) {
                    float d = 2.f * acc[mi][ni][r] - sn - sm[ni];
                    int c = cb + ni * 16;
                    D[(size_t)row * NPTS + c] = d;
                    if (bx != by) D[(size_t)c * NPTS + row] = d;
                }
            }
        }
    } else {
        // ---- st tile: P[point m, weight-row n] over 2O cols ----
        int isf = *flag;
        int nCol = (2 * O) >> 7;
        int s = bi - 36;
        int n0 = (s % nCol) * 128;   // weight-row tile (over 2O)
        int m0 = (s / nCol) * 128;   // point tile (over 1024)
        int N2 = 2 * O;
        float* P = Pg + (size_t)z * NPTS * N2;
        for (int k0 = 0; k0 < Kpad; k0 += 32) {
            __syncthreads();
            fill128(Ah, Xh + (size_t)m0 * ld + k0, ld);
            fill128(Al, Xl + (size_t)m0 * ld + k0, ld);
            fill128(Bh, Whi + (size_t)n0 * Kpad + k0, Kpad);
            if (isf) fill128(Bl, Wlo + (size_t)n0 * Kpad + k0, Kpad);
            __syncthreads();
            v8bf ah[4], al[4];
#pragma unroll
            for (int mi = 0; mi < 4; mi++) {
                ah[mi] = ldf(Ah, wr * 4 + mi, l);
                al[mi] = ldf(Al, wr * 4 + mi, l);
            }
#pragma unroll
            for (int ni = 0; ni < 4; ni++) {
                v8bf bh = ldf(Bh, wc * 4 + ni, l);
#pragma unroll
                for (int mi = 0; mi < 4; mi++) {
                    acc[mi][ni] = __builtin_amdgcn_mfma_f32_16x16x32_bf16(ah[mi], bh, acc[mi][ni], 0, 0, 0);
                    acc[mi][ni] = __builtin_amdgcn_mfma_f32_16x16x32_bf16(al[mi], bh, acc[mi][ni], 0, 0, 0);
                }
                if (isf) {
                    v8bf bl = ldf(Bl, wc * 4 + ni, l);
#pragma unroll
                    for (int mi = 0; mi < 4; mi++)
                        acc[mi][ni] = __builtin_amdgcn_mfma_f32_16x16x32_bf16(ah[mi], bl, acc[mi][ni], 0, 0, 0);
                }
            }
        }
        int rb = m0 + wr * 64 + quad * 4;
        int cb = n0 + wc * 64 + col;
#pragma unroll
        for (int mi = 0; mi < 4; mi++)
#pragma unroll
            for (int r = 0; r < 4; r++) {
                int row = rb + mi * 16 + r;
#pragma unroll
                for (int ni = 0; ni < 4; ni++)
                    P[(size_t)row * N2 + cb + ni * 16] = acc[mi][ni][r];
            }
    }
}

// ---------------- fused stage B: top-20 (wave per row, 4 rows/block) + gather-max ----------------
// 1D grid 1024, XCD-pinned: z = (i>>1)&3, local = ((i>>3)<<1)|(i&1); rows local*4+q (wave q)
__global__ __launch_bounds__(256) void k_layer_b(const float* __restrict__ Dg, const float* __restrict__ Pg,
                                                 const void* __restrict__ g, const void* __restrict__ bias,
                                                 int O, bf16* __restrict__ xhOut, bf16* __restrict__ xlOut,
                                                 float* __restrict__ sqOut, int writeSq,
                                                 const int* __restrict__ flag) {
    __shared__ int ids[4][20];
    __shared__ float sqP[4][8];
    int isf = *flag;
    int i = blockIdx.x;
    int z = (i >> 1) & 3;
    int local = ((i >> 3) << 1) | (i & 1);
    int tid = threadIdx.x;
    int wq = tid >> 6, l = tid & 63;
    int row = local * 4 + wq;

    // ---- per-wave register-resident top-20 (float4 loads; selection semantics identical:
    //      lane->index map bi = jj*256 + l*4 + q is bijective over [0,1024), monotone per
    //      lane in scan order -> min-index tie-break preserved; butterfly uses global bi) ----
    {
        const float* Dr = Dg + (size_t)z * NPTS * NPTS + (size_t)row * NPTS;
        float v[16];
#pragma unroll
        for (int jj = 0; jj < 4; jj++) {
            float4 f4 = *(const float4*)(Dr + jj * 256 + l * 4);
            v[jj * 4 + 0] = f4.x; v[jj * 4 + 1] = f4.y;
            v[jj * 4 + 2] = f4.z; v[jj * 4 + 3] = f4.w;
        }
        for (int s = 0; s < 20; s++) {
            float bv = v[0]; int bj = 0;
#pragma unroll
            for (int j = 1; j < 16; j++)
                if (v[j] > bv) { bv = v[j]; bj = j; }   // ascending keeps min global idx on tie
            int bi = (bj >> 2) * 256 + l * 4 + (bj & 3);
#pragma unroll
            for (int off = 1; off < 64; off <<= 1) {   // xor butterfly: all lanes converge
                float ov = __shfl_xor(bv, off);
                int   oi = __shfl_xor(bi, off);
                if (ov > bv || (ov == bv && oi < bi)) { bv = ov; bi = oi; }
            }
            if (l == 0) ids[wq][s] = bi;
            if (((bi >> 2) & 63) == l) {               // owning lane evicts
                int ej = (bi >> 8) * 4 + (bi & 3);
#pragma unroll
                for (int j = 0; j < 16; j++)
                    if (j == ej) v[j] = -__builtin_inff();
            }
        }
    }
    __syncthreads();

    // ---- gather + affine + lrelu + max over k for the block's 4 rows ----
    int N2 = 2 * O;
    const float* P = Pg + (size_t)z * NPTS * N2;
    for (int it = tid; it < 4 * O; it += 256) {
        int r = it / O, o = it % O;         // wave-contiguous: one row+chunk per wave
        int n = local * 4 + r;
        float tv = P[(size_t)n * N2 + O + o] - P[(size_t)n * N2 + o];
        float scl = ldw(g, o, isf) * BN_SCALE;
        float bb = ldw(bias, o, isf);
        float acc = -__builtin_inff();
        for (int j = 0; j < 20; j++) {
            int m = ids[r][j];
            float v = P[(size_t)m * N2 + o] + tv;
            float z2 = v * scl + bb;
            z2 = z2 > 0.f ? z2 : 0.2f * z2;
            acc = fmaxf(acc, z2);
        }
        bf16 hi = f2b(acc);
        bf16 lo = f2b(acc - b2f(hi));
        xhOut[(size_t)z * NPTS * 960 + (size_t)n * 960 + o] = hi;
        xlOut[(size_t)z * NPTS * 960 + (size_t)n * 960 + o] = lo;
        if (writeSq) {
            float xv = b2f(hi) + b2f(lo);
            float s = xv * xv;
#pragma unroll
            for (int off = 32; off > 0; off >>= 1) s += __shfl_down(s, off);
            if (l == 0) sqP[r][o >> 6] = s;   // fixed chunk slot: deterministic order
        }
    }
    if (writeSq) {
        __syncthreads();
        if (tid < 4) {
            int nc = O >> 6;
            float tot = 0.f;
            for (int c = 0; c < nc; c++) tot += sqP[tid][c];
            sqOut[z * NPTS + local * 4 + tid] = tot;
        }
    }
}

// ---------------- conv5 via MFMA (pre-split W5) + fused affine/lrelu/max-pool ----------------
// 1D grid 128, XCD-pinned: z = (i>>1)&3, wi = ((i>>3)<<1)|(i&1); o0=(wi&3)*128, m0=(wi>>2)*128
// 128x128 tile, 4 waves 2x2 (each 64x64)
__global__ __launch_bounds__(256) void k_conv5(const bf16* __restrict__ Xhi, const bf16* __restrict__ Xlo,
                                               const bf16* __restrict__ Whi, const bf16* __restrict__ Wlo,
                                               const void* __restrict__ g, const void* __restrict__ bias,
                                               unsigned* __restrict__ pooledU,
                                               const int* __restrict__ flag) {
    int isf = *flag;
    int i = blockIdx.x;
    int z = (i >> 1) & 3;
    int wi = ((i >> 3) << 1) | (i & 1);
    int o0 = (wi & 3) * 128, m0 = (wi >> 2) * 128;
    const bf16* Xh = Xhi + (size_t)z * NPTS * 960;
    const bf16* Xl = Xlo + (size_t)z * NPTS * 960;
    __shared__ alignas(16) bf16 Ah[128 * TW], Al[128 * TW], Bh[128 * TW], Bl[128 * TW];
    __shared__ float red[4][4][16];
    int w = threadIdx.x >> 6, l = threadIdx.x & 63;
    int wr = w >> 1, wc = w & 1;
    int quad = l >> 4, col = l & 15;
    v4f zero = {0.f, 0.f, 0.f, 0.f};
    v4f acc[4][4] = {{zero, zero, zero, zero}, {zero, zero, zero, zero},
                     {zero, zero, zero, zero}, {zero, zero, zero, zero}};
    for (int k0 = 0; k0 < 960; k0 += 32) {
        __syncthreads();
        fill128(Ah, Xh + (size_t)m0 * 960 + k0, 960);
        fill128(Al, Xl + (size_t)m0 * 960 + k0, 960);
        fill128(Bh, Whi + (size_t)o0 * 960 + k0, 960);
        if (isf) fill128(Bl, Wlo + (size_t)o0 * 960 + k0, 960);
        __syncthreads();
        v8bf ah[4], al[4];
#pragma unroll
        for (int mi = 0; mi < 4; mi++) {
            ah[mi] = ldf(Ah, wr * 4 + mi, l);
            al[mi] = ldf(Al, wr * 4 + mi, l);
        }
#pragma unroll
        for (int ni = 0; ni < 4; ni++) {
            v8bf bh = ldf(Bh, wc * 4 + ni, l);
#pragma unroll
            for (int mi = 0; mi < 4; mi++) {
                acc[mi][ni] = __builtin_amdgcn_mfma_f32_16x16x32_bf16(ah[mi], bh, acc[mi][ni], 0, 0, 0);
                acc[mi][ni] = __builtin_amdgcn_mfma_f32_16x16x32_bf16(al[mi], bh, acc[mi][ni], 0, 0, 0);
            }
            if (isf) {
                v8bf bl = ldf(Bl, wc * 4 + ni, l);
#pragma unroll
                for (int mi = 0; mi < 4; mi++)
                    acc[mi][ni] = __builtin_amdgcn_mfma_f32_16x16x32_bf16(ah[mi], bl, acc[mi][ni], 0, 0, 0);
            }
        }
    }
    // affine + lrelu + max over this block's 128 rows for each of its 128 cols
#pragma unroll
    for (int ni = 0; ni < 4; ni++) {
        int o = o0 + wc * 64 + ni * 16 + col;
        float scl = ldw(g, o, isf) * BN_SCALE;
        float bi = ldw(bias, o, isf);
        float ym = -__builtin_inff();
#pragma unroll
        for (int mi = 0; mi < 4; mi++)
#pragma unroll
            for (int r = 0; r < 4; r++) {
                float v = acc[mi][ni][r] * scl + bi;
                v = v > 0.f ? v : 0.2f * v;
                ym = fmaxf(ym, v);
            }
        ym = fmaxf(ym, __shfl_down(ym, 32));   // reduce over quads (rows)
        ym = fmaxf(ym, __shfl_down(ym, 16));
        if (quad == 0) red[w][ni][col] = ym;
    }
    __syncthreads();
    if (threadIdx.x < 128) {
        // waves {0,2} share cols o0..o0+63; waves {1,3} share o0+64..o0+127
        int wcs = threadIdx.x >> 6, ni = (threadIdx.x >> 4) & 3, c = threadIdx.x & 15;
        float m = fmaxf(red[wcs][ni][c], red[wcs + 2][ni][c]);
        atomicMax(&pooledU[z * 512 + o0 + wcs * 64 + ni * 16 + c], ordf(m));
    }
}

// ---------------- final linear: coalesced wave-per-output ----------------
__global__ void k_final(const unsigned* __restrict__ pooledU, const void* __restrict__ We,
                        void* __restrict__ out, const int* __restrict__ flag) {
    __shared__ float p[512];
    int isf = *flag;
    int b = blockIdx.x >> 2, fb = blockIdx.x & 3;
    int t = threadIdx.x, w = t >> 6, l = t & 63;
    for (int i = t; i < 512; i += 256) p[i] = iordf(pooledU[b * 512 + i]);
    __syncthreads();
    for (int it = 0; it < 16; it++) {
        int f = fb * 64 + w * 16 + it;
        float s = 0.f;
        size_t base = (size_t)f * 512 + l * 8;
#pragma unroll
        for (int j = 0; j < 8; j++) s += p[l * 8 + j] * ldw(We, base + j, isf);
#pragma unroll
        for (int off = 32; off > 0; off >>= 1) s += __shfl_down(s, off);
        if (l == 0) {
            if (isf) ((float*)out)[b * 256 + f] = s;
            else     ((bf16*)out)[b * 256 + f] = f2b(s);
        }
    }
}

extern "C" void kernel_launch(void* const* d_in, const int* in_sizes, int n_in,
                              void* d_out, int out_size, void* d_ws, size_t ws_size,
                              hipStream_t stream) {
    const void* x  = d_in[0];
    const void* Wl[4] = { d_in[1], d_in[4], d_in[7], d_in[10] };
    const void* gl[4] = { d_in[2], d_in[5], d_in[8], d_in[11] };
    const void* bl[4] = { d_in[3], d_in[6], d_in[9], d_in[12] };
    const void* W5 = d_in[13];
    const void* g5 = d_in[14];
    const void* b5 = d_in[15];
    const void* We = d_in[16];

    // workspace layout (bytes), total ~53.5 MB (ws ~256 MiB per round-9 fill evidence)
    char* base = (char*)d_ws;
    bf16*     xc_hi   = (bf16*)(base);                  // 7,864,320
    bf16*     xc_lo   = (bf16*)(base + 7864320);        // 7,864,320
    bf16*     xpadh   = (bf16*)(base + 15728640);       // 262,144
    bf16*     xpadl   = (bf16*)(base + 15990784);       // 262,144
    float*    Dbuf    = (float*)(base + 16252928);      // 16,777,216
    float*    Pbuf    = (float*)(base + 33030144);      // 16,777,216
    bf16*     Whi     = (bf16*)(base + 49807360);       // 1,679,360
    bf16*     Wlo     = (bf16*)(base + 51486720);       // 1,679,360
    unsigned* pooledU = (unsigned*)(base + 53493760);   // 8,192
    float*    sq      = (float*)(base + 53501952);      // 16,384
    int*      flag    = (int*)(base + 53518336);        // 4

    const int Kpad[4]   = { 32, 64, 128, 256 };
    const int Os[4]     = { 64, 128, 256, 512 };
    const int Woff[5]   = { 0, 4096, 20480, 86016, 348160 };
    const int colIn[4]  = { 0, 0, 64, 192 };
    const int colOut[4] = { 0, 64, 192, 448 };

    k_prep<<<3296, 256, 0, stream>>>(Wl[0], Wl[1], Wl[2], Wl[3], W5, x,
                                     Whi, Wlo, xpadh, xpadl, sq, flag, pooledU);

    for (int l = 0; l < 4; l++) {
        int O = Os[l];
        int nCol = (2 * O) >> 7;
        int nBlk = 36 + 8 * nCol;  // 44/52/68/100 -> *4 divisible by 8 for XCD decode
        const bf16* Xh = (l == 0) ? xpadh : (xc_hi + colIn[l]);
        const bf16* Xl = (l == 0) ? xpadl : (xc_lo + colIn[l]);
        int ld = (l == 0) ? 32 : 960;
        size_t xstr = (l == 0) ? (size_t)NPTS * 32 : (size_t)NPTS * 960;
        k_layer_a<<<nBlk * NB, 256, 0, stream>>>(
            Xh, Xl, ld, Kpad[l], xstr, Whi + Woff[l], Wlo + Woff[l], O, sq, Dbuf, Pbuf, flag);
        k_layer_b<<<NPTS * NB / 4, 256, 0, stream>>>(
            Dbuf, Pbuf, gl[l], bl[l], O, xc_hi + colOut[l], xc_lo + colOut[l], sq, l < 3, flag);
    }
    k_conv5<<<128, 256, 0, stream>>>(xc_hi, xc_lo, Whi + Woff[4], Wlo + Woff[4],
                                     g5, b5, pooledU, flag);
    k_final<<<16, 256, 0, stream>>>(pooledU, We, d_out, flag);
}

// Round 3
// 353.194 us; speedup vs baseline: 1.0236x; 1.0236x over previous
//
#include <hip/hip_runtime.h>
#include <hip/hip_bf16.h>
#include <math.h>

typedef __hip_bfloat16 bf16;
typedef __bf16 v8bf __attribute__((ext_vector_type(8)));
typedef float v4f __attribute__((ext_vector_type(4)));

#define BN_SCALE 0.9999950000374997f
#define NPTS 1024
#define NB 4
#define CH5 ((size_t)4 * 1024 * 512)   // conv5 partial-chunk stride (floats)

__device__ __forceinline__ float b2f(bf16 v) { return __bfloat162float(v); }
__device__ __forceinline__ bf16 f2b(float v) { return __float2bfloat16(v); }
__device__ __forceinline__ float ldw(const void* p, size_t i, int isf) {
    return isf ? ((const float*)p)[i] : b2f(((const bf16*)p)[i]);
}
__device__ __forceinline__ unsigned ordf(float f) {
    unsigned u = __float_as_uint(f);
    return (u & 0x80000000u) ? ~u : (u | 0x80000000u);
}
__device__ __forceinline__ float iordf(unsigned u) {
    return (u & 0x80000000u) ? __uint_as_float(u ^ 0x80000000u) : __uint_as_float(~u);
}

// per-block dtype detect from first 512 shorts of x (fp32 ~113/256 implausible, bf16 ~0)
__device__ __forceinline__ int detect_isf(const void* xraw, int* cnt) {
    const unsigned short* u = (const unsigned short*)xraw;
    int t = threadIdx.x, c = 0;
    for (int i = t; i < 512; i += 256) {
        unsigned short v = u[i];
        int e = (v >> 7) & 0xFF;
        int m = v & 0x7F;
        if (e == 0xFF || e >= 141 || (e == 0 && m != 0)) c++;
    }
    cnt[t] = c;
    __syncthreads();
    for (int off = 128; off > 0; off >>= 1) {
        if (t < off) cnt[t] += cnt[t + off];
        __syncthreads();
    }
    int isf = (cnt[0] > 30) ? 1 : 0;
    __syncthreads();
    return isf;
}

// ---------------- fused prep: dtype flag + pooled init + weight splits + x pad + sq ----------------
__global__ void k_prep(const void* __restrict__ W1, const void* __restrict__ W2,
                       const void* __restrict__ W3, const void* __restrict__ W4,
                       const void* __restrict__ W5, const void* __restrict__ x,
                       bf16* __restrict__ Whi, bf16* __restrict__ Wlo,
                       bf16* __restrict__ xph, bf16* __restrict__ xpl, float* __restrict__ sq,
                       int* __restrict__ flag, unsigned* __restrict__ pooledU) {
    __shared__ int cnt[256];
    int isf = detect_isf(x, cnt);
    if (blockIdx.x == 0) {
        if (threadIdx.x == 0) *flag = isf;
        for (int i = threadIdx.x; i < 2048; i += 256) pooledU[i] = 0u;  // 0 < ordf(any finite)
    }
    int idx = blockIdx.x * 256 + threadIdx.x;
    if (idx < 839680) {
        const void* src; int C, O, Kpad, two, local;
        if (idx < 4096)        { src = W1; C = 3;   O = 64;  Kpad = 32;  two = 1; local = idx; }
        else if (idx < 20480)  { src = W2; C = 64;  O = 128; Kpad = 64;  two = 1; local = idx - 4096; }
        else if (idx < 86016)  { src = W3; C = 128; O = 256; Kpad = 128; two = 1; local = idx - 20480; }
        else if (idx < 348160) { src = W4; C = 256; O = 512; Kpad = 256; two = 1; local = idx - 86016; }
        else                   { src = W5; C = 960; O = 512; Kpad = 960; two = 0; local = idx - 348160; }
        int r = local / Kpad, c = local % Kpad;
        float wv = 0.f;
        if (c < C) {
            size_t off;
            if (two) off = (r < O) ? (size_t)r * 2 * C + c : (size_t)(r - O) * 2 * C + C + c;
            else     off = (size_t)r * C + c;
            wv = ldw(src, off, isf);
        }
        bf16 h = f2b(wv);
        Whi[idx] = h;
        Wlo[idx] = f2b(wv - b2f(h));
    } else if (idx < 843776) {
        int p = idx - 839680;       // point index: z*1024 + n
        int z = p >> 10, n = p & 1023;
        bf16* ph = xph + (size_t)z * NPTS * 32;
        bf16* pl = xpl + (size_t)z * NPTS * 32;
        float s = 0.f;
        for (int c = 0; c < 32; c++) {
            float v = (c < 3) ? ldw(x, (size_t)z * NPTS * 3 + n * 3 + c, isf) : 0.f;
            bf16 h = f2b(v);
            ph[n * 32 + c] = h;
            pl[n * 32 + c] = f2b(v - b2f(h));
            s += v * v;
        }
        sq[z * NPTS + n] = s;
    }
}

// ---- conflict-free LDS layout: k-quad-major [kq][row][8], XOR-swizzled ----
// element index for (plane=k-quad, row): 16B unit = (plane*128+row) ^ (plane<<1)
// reads: each quad's 16 lanes hit 16 CONSECUTIVE 16B units -> 0 conflicts
// writes: subgroup spread over 8 distinct bank-groups -> 0 conflicts
__device__ __forceinline__ int lidx(int plane, int row) {
    return ((((plane << 7) | row)) ^ (plane << 1)) << 3;
}
// fill a 128x32 bf16 tile (rows stride ld) into LDS [4][128][8]; 256 threads x 2 x 16B
__device__ __forceinline__ void fill128(bf16* dst, const bf16* src, int ld) {
    int t = threadIdx.x;
    int r = t >> 2, kq = t & 3;
    *(float4*)(dst + lidx(kq, r))      = *(const float4*)(src + (size_t)r * ld + kq * 8);
    *(float4*)(dst + lidx(kq, r + 64)) = *(const float4*)(src + (size_t)(r + 64) * ld + kq * 8);
}
// MFMA fragment: sub-tile 'sub' (16 rows of 128), lane l: row=sub*16+(l&15), k=(l>>4)*8..+7
__device__ __forceinline__ v8bf ldf(const bf16* tile, int sub, int l) {
    return *(const v8bf*)(tile + lidx(l >> 4, sub * 16 + (l & 15)));
}

// ---------------- fused layer stage A: dist (upper-tri 128x128 tiles) + st ----------------
// 1D grid, XCD-pinned: z = (i>>1)&3, bi = ((i>>3)<<1)|(i&1)  (batch z -> XCDs {2z,2z+1})
// 128x128 output tile, 4 waves in 2x2, each wave 64x64 (acc[4][4])
__global__ __launch_bounds__(256) void k_layer_a(const bf16* __restrict__ Xhi, const bf16* __restrict__ Xlo,
                                                 int ld, int Kpad, size_t xstride,
                                                 const bf16* __restrict__ Whi, const bf16* __restrict__ Wlo,
                                                 int O, const float* __restrict__ sqg,
                                                 float* __restrict__ Dg, float* __restrict__ Pg,
                                                 const int* __restrict__ flag) {
    int i = blockIdx.x;
    int z = (i >> 1) & 3;
    int bi = ((i >> 3) << 1) | (i & 1);
    const bf16* Xh = Xhi + (size_t)z * xstride;
    const bf16* Xl = Xlo + (size_t)z * xstride;
    __shared__ alignas(16) bf16 Ah[4096], Al[4096], Bh[4096], Bl[4096];
    int w = threadIdx.x >> 6, l = threadIdx.x & 63;
    int wr = w >> 1, wc = w & 1;
    int quad = l >> 4, col = l & 15;
    v4f zero = {0.f, 0.f, 0.f, 0.f};
    v4f acc[4][4] = {{zero, zero, zero, zero}, {zero, zero, zero, zero},
                     {zero, zero, zero, zero}, {zero, zero, zero, zero}};

    if (bi < 36) {
        // ---- dist tile: triangular decode over 8x8, bx >= by ----
        int bx = 0;
        while ((((bx + 1) * (bx + 2)) >> 1) <= bi) bx++;
        int by = bi - ((bx * (bx + 1)) >> 1);
        const float* sq = sqg + z * NPTS;
        float* D = Dg + (size_t)z * NPTS * NPTS;
        int n0 = by * 128, m0 = bx * 128;
        for (int k0 = 0; k0 < Kpad; k0 += 32) {
            __syncthreads();
            fill128(Ah, Xh + (size_t)n0 * ld + k0, ld);
            fill128(Bh, Xh + (size_t)m0 * ld + k0, ld);
            fill128(Al, Xl + (size_t)n0 * ld + k0, ld);
            fill128(Bl, Xl + (size_t)m0 * ld + k0, ld);
            __syncthreads();
            v8bf ah[4], al[4];
#pragma unroll
            for (int mi = 0; mi < 4; mi++) {
                ah[mi] = ldf(Ah, wr * 4 + mi, l);
                al[mi] = ldf(Al, wr * 4 + mi, l);
            }
#pragma unroll
            for (int ni = 0; ni < 4; ni++) {
                v8bf bh = ldf(Bh, wc * 4 + ni, l);
                v8bf bl = ldf(Bl, wc * 4 + ni, l);
#pragma unroll
                for (int mi = 0; mi < 4; mi++) {
                    acc[mi][ni] = __builtin_amdgcn_mfma_f32_16x16x32_bf16(ah[mi], bh, acc[mi][ni], 0, 0, 0);
                    acc[mi][ni] = __builtin_amdgcn_mfma_f32_16x16x32_bf16(ah[mi], bl, acc[mi][ni], 0, 0, 0);
                    acc[mi][ni] = __builtin_amdgcn_mfma_f32_16x16x32_bf16(al[mi], bh, acc[mi][ni], 0, 0, 0);
                }
            }
        }
        int rb = n0 + wr * 64 + quad * 4;
        int cb = m0 + wc * 64 + col;
        float sm[4];
#pragma unroll
        for (int ni = 0; ni < 4; ni++) sm[ni] = sq[cb + ni * 16];
#pragma unroll
        for (int mi = 0; mi < 4; mi++) {
#pragma unroll
            for (int r = 0; r < 4; r++) {
                int row = rb + mi * 16 + r;
                float sn = sq[row];
#pragma unroll
                for (int ni = 0; ni < 4; ni++) {
                    float d = 2.f * acc[mi][ni][r] - sn - sm[ni];
                    int c = cb + ni * 16;
                    D[(size_t)row * NPTS + c] = d;
                    if (bx != by) D[(size_t)c * NPTS + row] = d;
                }
            }
        }
    } else {
        // ---- st tile: P[point m, weight-row n] over 2O cols ----
        int isf = *flag;
        int nCol = (2 * O) >> 7;
        int s = bi - 36;
        int n0 = (s % nCol) * 128;   // weight-row tile (over 2O)
        int m0 = (s / nCol) * 128;   // point tile (over 1024)
        int N2 = 2 * O;
        float* P = Pg + (size_t)z * NPTS * N2;
        for (int k0 = 0; k0 < Kpad; k0 += 32) {
            __syncthreads();
            fill128(Ah, Xh + (size_t)m0 * ld + k0, ld);
            fill128(Al, Xl + (size_t)m0 * ld + k0, ld);
            fill128(Bh, Whi + (size_t)n0 * Kpad + k0, Kpad);
            if (isf) fill128(Bl, Wlo + (size_t)n0 * Kpad + k0, Kpad);
            __syncthreads();
            v8bf ah[4], al[4];
#pragma unroll
            for (int mi = 0; mi < 4; mi++) {
                ah[mi] = ldf(Ah, wr * 4 + mi, l);
                al[mi] = ldf(Al, wr * 4 + mi, l);
            }
#pragma unroll
            for (int ni = 0; ni < 4; ni++) {
                v8bf bh = ldf(Bh, wc * 4 + ni, l);
#pragma unroll
                for (int mi = 0; mi < 4; mi++) {
                    acc[mi][ni] = __builtin_amdgcn_mfma_f32_16x16x32_bf16(ah[mi], bh, acc[mi][ni], 0, 0, 0);
                    acc[mi][ni] = __builtin_amdgcn_mfma_f32_16x16x32_bf16(al[mi], bh, acc[mi][ni], 0, 0, 0);
                }
                if (isf) {
                    v8bf bl = ldf(Bl, wc * 4 + ni, l);
#pragma unroll
                    for (int mi = 0; mi < 4; mi++)
                        acc[mi][ni] = __builtin_amdgcn_mfma_f32_16x16x32_bf16(ah[mi], bl, acc[mi][ni], 0, 0, 0);
                }
            }
        }
        int rb = m0 + wr * 64 + quad * 4;
        int cb = n0 + wc * 64 + col;
#pragma unroll
        for (int mi = 0; mi < 4; mi++)
#pragma unroll
            for (int r = 0; r < 4; r++) {
                int row = rb + mi * 16 + r;
#pragma unroll
                for (int ni = 0; ni < 4; ni++)
                    P[(size_t)row * N2 + cb + ni * 16] = acc[mi][ni][r];
            }
    }
}

// ---------------- fused stage B: top-20 (wave per row, 4 rows/block) + gather-max ----------------
// 1D grid 1024, XCD-pinned: z = (i>>1)&3, local = ((i>>3)<<1)|(i&1); rows local*4+q (wave q)
__global__ __launch_bounds__(256) void k_layer_b(const float* __restrict__ Dg, const float* __restrict__ Pg,
                                                 const void* __restrict__ g, const void* __restrict__ bias,
                                                 int O, bf16* __restrict__ xhOut, bf16* __restrict__ xlOut,
                                                 float* __restrict__ sqOut, int writeSq,
                                                 const int* __restrict__ flag) {
    __shared__ int ids[4][20];
    __shared__ float sqP[4][8];
    int isf = *flag;
    int i = blockIdx.x;
    int z = (i >> 1) & 3;
    int local = ((i >> 3) << 1) | (i & 1);
    int tid = threadIdx.x;
    int wq = tid >> 6, l = tid & 63;
    int row = local * 4 + wq;

    // ---- per-wave register-resident top-20 (float4 loads; selection semantics identical:
    //      lane->index map bi = jj*256 + l*4 + q is bijective over [0,1024), monotone per
    //      lane in scan order -> min-index tie-break preserved; butterfly uses global bi) ----
    {
        const float* Dr = Dg + (size_t)z * NPTS * NPTS + (size_t)row * NPTS;
        float v[16];
#pragma unroll
        for (int jj = 0; jj < 4; jj++) {
            float4 f4 = *(const float4*)(Dr + jj * 256 + l * 4);
            v[jj * 4 + 0] = f4.x; v[jj * 4 + 1] = f4.y;
            v[jj * 4 + 2] = f4.z; v[jj * 4 + 3] = f4.w;
        }
        for (int s = 0; s < 20; s++) {
            float bv = v[0]; int bj = 0;
#pragma unroll
            for (int j = 1; j < 16; j++)
                if (v[j] > bv) { bv = v[j]; bj = j; }   // ascending keeps min global idx on tie
            int bi = (bj >> 2) * 256 + l * 4 + (bj & 3);
#pragma unroll
            for (int off = 1; off < 64; off <<= 1) {   // xor butterfly: all lanes converge
                float ov = __shfl_xor(bv, off);
                int   oi = __shfl_xor(bi, off);
                if (ov > bv || (ov == bv && oi < bi)) { bv = ov; bi = oi; }
            }
            if (l == 0) ids[wq][s] = bi;
            if (((bi >> 2) & 63) == l) {               // owning lane evicts
                int ej = (bi >> 8) * 4 + (bi & 3);
#pragma unroll
                for (int j = 0; j < 16; j++)
                    if (j == ej) v[j] = -__builtin_inff();
            }
        }
    }
    __syncthreads();

    // ---- gather + affine + lrelu + max over k for the block's 4 rows ----
    int N2 = 2 * O;
    const float* P = Pg + (size_t)z * NPTS * N2;
    for (int it = tid; it < 4 * O; it += 256) {
        int r = it / O, o = it % O;         // wave-contiguous: one row+chunk per wave
        int n = local * 4 + r;
        float tv = P[(size_t)n * N2 + O + o] - P[(size_t)n * N2 + o];
        float scl = ldw(g, o, isf) * BN_SCALE;
        float bb = ldw(bias, o, isf);
        float acc = -__builtin_inff();
        for (int j = 0; j < 20; j++) {
            int m = ids[r][j];
            float v = P[(size_t)m * N2 + o] + tv;
            float z2 = v * scl + bb;
            z2 = z2 > 0.f ? z2 : 0.2f * z2;
            acc = fmaxf(acc, z2);
        }
        bf16 hi = f2b(acc);
        bf16 lo = f2b(acc - b2f(hi));
        xhOut[(size_t)z * NPTS * 960 + (size_t)n * 960 + o] = hi;
        xlOut[(size_t)z * NPTS * 960 + (size_t)n * 960 + o] = lo;
        if (writeSq) {
            float xv = b2f(hi) + b2f(lo);
            float s = xv * xv;
#pragma unroll
            for (int off = 32; off > 0; off >>= 1) s += __shfl_down(s, off);
            if (l == 0) sqP[r][o >> 6] = s;   // fixed chunk slot: deterministic order
        }
    }
    if (writeSq) {
        __syncthreads();
        if (tid < 4) {
            int nc = O >> 6;
            float tot = 0.f;
            for (int c = 0; c < nc; c++) tot += sqP[tid][c];
            sqOut[z * NPTS + local * 4 + tid] = tot;
        }
    }
}

// ---------------- conv5 via MFMA, K-split x6 (chunks of 160) -> f32 partials ----------------
// 1D grid 768, XCD-pinned: z=(i>>1)&3, rest=((i>>3)<<1)|(i&1) in [0,192):
//   ks = rest>>5 (K-chunk), tile = rest&31: m0=(tile>>2)*128, o0=(tile&3)*128
__global__ __launch_bounds__(256) void k_conv5(const bf16* __restrict__ Xhi, const bf16* __restrict__ Xlo,
                                               const bf16* __restrict__ Whi, const bf16* __restrict__ Wlo,
                                               float* __restrict__ P5,
                                               const int* __restrict__ flag) {
    int isf = *flag;
    int i = blockIdx.x;
    int z = (i >> 1) & 3;
    int rest = ((i >> 3) << 1) | (i & 1);
    int ks = rest >> 5;
    int tile = rest & 31;
    int m0 = (tile >> 2) * 128, o0 = (tile & 3) * 128;
    const bf16* Xh = Xhi + (size_t)z * NPTS * 960;
    const bf16* Xl = Xlo + (size_t)z * NPTS * 960;
    __shared__ alignas(16) bf16 Ah[4096], Al[4096], Bh[4096], Bl[4096];
    int w = threadIdx.x >> 6, l = threadIdx.x & 63;
    int wr = w >> 1, wc = w & 1;
    int quad = l >> 4, col = l & 15;
    v4f zero = {0.f, 0.f, 0.f, 0.f};
    v4f acc[4][4] = {{zero, zero, zero, zero}, {zero, zero, zero, zero},
                     {zero, zero, zero, zero}, {zero, zero, zero, zero}};
    int kbeg = ks * 160, kend = kbeg + 160;
    for (int k0 = kbeg; k0 < kend; k0 += 32) {
        __syncthreads();
        fill128(Ah, Xh + (size_t)m0 * 960 + k0, 960);
        fill128(Al, Xl + (size_t)m0 * 960 + k0, 960);
        fill128(Bh, Whi + (size_t)o0 * 960 + k0, 960);
        if (isf) fill128(Bl, Wlo + (size_t)o0 * 960 + k0, 960);
        __syncthreads();
        v8bf ah[4], al[4];
#pragma unroll
        for (int mi = 0; mi < 4; mi++) {
            ah[mi] = ldf(Ah, wr * 4 + mi, l);
            al[mi] = ldf(Al, wr * 4 + mi, l);
        }
#pragma unroll
        for (int ni = 0; ni < 4; ni++) {
            v8bf bh = ldf(Bh, wc * 4 + ni, l);
#pragma unroll
            for (int mi = 0; mi < 4; mi++) {
                acc[mi][ni] = __builtin_amdgcn_mfma_f32_16x16x32_bf16(ah[mi], bh, acc[mi][ni], 0, 0, 0);
                acc[mi][ni] = __builtin_amdgcn_mfma_f32_16x16x32_bf16(al[mi], bh, acc[mi][ni], 0, 0, 0);
            }
            if (isf) {
                v8bf bl = ldf(Bl, wc * 4 + ni, l);
#pragma unroll
                for (int mi = 0; mi < 4; mi++)
                    acc[mi][ni] = __builtin_amdgcn_mfma_f32_16x16x32_bf16(ah[mi], bl, acc[mi][ni], 0, 0, 0);
            }
        }
    }
    // write f32 partial tile (disjoint per (ks,z,tile) -> no atomics)
    float* Pw = P5 + (size_t)ks * CH5 + (size_t)z * NPTS * 512;
    int rb = m0 + wr * 64 + quad * 4;
    int cb = o0 + wc * 64 + col;
#pragma unroll
    for (int mi = 0; mi < 4; mi++)
#pragma unroll
        for (int r = 0; r < 4; r++) {
            int row = rb + mi * 16 + r;
#pragma unroll
            for (int ni = 0; ni < 4; ni++)
                Pw[(size_t)row * 512 + cb + ni * 16] = acc[mi][ni][r];
        }
}

// ---------------- pool5: sum 6 K-chunks + affine + lrelu + max over rows -> pooled ----------------
// 1D grid 128, XCD-pinned: z=(i>>1)&3, rest=((i>>3)<<1)|(i&1) in [0,32):
//   oc=(rest&3)*128 cols, mc=(rest>>2)*128 rows; thread: col=t&127, half=t>>7 (64 rows)
__global__ __launch_bounds__(256) void k_pool5(const float* __restrict__ P5,
                                               const void* __restrict__ g, const void* __restrict__ bias,
                                               unsigned* __restrict__ pooledU,
                                               const int* __restrict__ flag) {
    __shared__ float red2[128];
    int isf = *flag;
    int i = blockIdx.x;
    int z = (i >> 1) & 3;
    int rest = ((i >> 3) << 1) | (i & 1);
    int oc = (rest & 3) * 128, mc = (rest >> 2) * 128;
    int t = threadIdx.x;
    int c = t & 127, h = t >> 7;
    int o = oc + c;
    float scl = ldw(g, o, isf) * BN_SCALE;
    float bb = ldw(bias, o, isf);
    const float* p0 = P5 + (size_t)z * NPTS * 512 + (size_t)(mc + h * 64) * 512 + o;
    float ym = -__builtin_inff();
    for (int r = 0; r < 64; r++) {
        const float* p = p0 + (size_t)r * 512;
        float s = p[0];
#pragma unroll
        for (int ks = 1; ks < 6; ks++) s += p[(size_t)ks * CH5];
        float v = s * scl + bb;
        v = v > 0.f ? v : 0.2f * v;
        ym = fmaxf(ym, v);
    }
    if (h == 1) red2[c] = ym;
    __syncthreads();
    if (h == 0) {
        float m = fmaxf(ym, red2[c]);
        atomicMax(&pooledU[z * 512 + o], ordf(m));
    }
}

// ---------------- final linear: coalesced wave-per-output ----------------
__global__ void k_final(const unsigned* __restrict__ pooledU, const void* __restrict__ We,
                        void* __restrict__ out, const int* __restrict__ flag) {
    __shared__ float p[512];
    int isf = *flag;
    int b = blockIdx.x >> 2, fb = blockIdx.x & 3;
    int t = threadIdx.x, w = t >> 6, l = t & 63;
    for (int i = t; i < 512; i += 256) p[i] = iordf(pooledU[b * 512 + i]);
    __syncthreads();
    for (int it = 0; it < 16; it++) {
        int f = fb * 64 + w * 16 + it;
        float s = 0.f;
        size_t base = (size_t)f * 512 + l * 8;
#pragma unroll
        for (int j = 0; j < 8; j++) s += p[l * 8 + j] * ldw(We, base + j, isf);
#pragma unroll
        for (int off = 32; off > 0; off >>= 1) s += __shfl_down(s, off);
        if (l == 0) {
            if (isf) ((float*)out)[b * 256 + f] = s;
            else     ((bf16*)out)[b * 256 + f] = f2b(s);
        }
    }
}

extern "C" void kernel_launch(void* const* d_in, const int* in_sizes, int n_in,
                              void* d_out, int out_size, void* d_ws, size_t ws_size,
                              hipStream_t stream) {
    const void* x  = d_in[0];
    const void* Wl[4] = { d_in[1], d_in[4], d_in[7], d_in[10] };
    const void* gl[4] = { d_in[2], d_in[5], d_in[8], d_in[11] };
    const void* bl[4] = { d_in[3], d_in[6], d_in[9], d_in[12] };
    const void* W5 = d_in[13];
    const void* g5 = d_in[14];
    const void* b5 = d_in[15];
    const void* We = d_in[16];

    // workspace layout (bytes), ~101.5 MB total (ws ~256 MiB per round-9 fill evidence)
    char* base = (char*)d_ws;
    bf16*     xc_hi   = (bf16*)(base);                  // 7,864,320
    bf16*     xc_lo   = (bf16*)(base + 7864320);        // 7,864,320
    bf16*     xpadh   = (bf16*)(base + 15728640);       // 262,144
    bf16*     xpadl   = (bf16*)(base + 15990784);       // 262,144
    float*    Dbuf    = (float*)(base + 16252928);      // 16,777,216
    float*    Pbuf    = (float*)(base + 33030144);      // 16,777,216
    bf16*     Whi     = (bf16*)(base + 49807360);       // 1,679,360
    bf16*     Wlo     = (bf16*)(base + 51486720);       // 1,679,360
    unsigned* pooledU = (unsigned*)(base + 53493760);   // 8,192
    float*    sq      = (float*)(base + 53501952);      // 16,384
    int*      flag    = (int*)(base + 53518336);        // 4
    float*    P5      = (float*)(base + 53520384);      // 50,331,648 (6 x 8 MB conv5 partials)

    const int Kpad[4]   = { 32, 64, 128, 256 };
    const int Os[4]     = { 64, 128, 256, 512 };
    const int Woff[5]   = { 0, 4096, 20480, 86016, 348160 };
    const int colIn[4]  = { 0, 0, 64, 192 };
    const int colOut[4] = { 0, 64, 192, 448 };

    k_prep<<<3296, 256, 0, stream>>>(Wl[0], Wl[1], Wl[2], Wl[3], W5, x,
                                     Whi, Wlo, xpadh, xpadl, sq, flag, pooledU);

    for (int l = 0; l < 4; l++) {
        int O = Os[l];
        int nCol = (2 * O) >> 7;
        int nBlk = 36 + 8 * nCol;  // 44/52/68/100 -> *4 divisible by 8 for XCD decode
        const bf16* Xh = (l == 0) ? xpadh : (xc_hi + colIn[l]);
        const bf16* Xl = (l == 0) ? xpadl : (xc_lo + colIn[l]);
        int ld = (l == 0) ? 32 : 960;
        size_t xstr = (l == 0) ? (size_t)NPTS * 32 : (size_t)NPTS * 960;
        k_layer_a<<<nBlk * NB, 256, 0, stream>>>(
            Xh, Xl, ld, Kpad[l], xstr, Whi + Woff[l], Wlo + Woff[l], O, sq, Dbuf, Pbuf, flag);
        k_layer_b<<<NPTS * NB / 4, 256, 0, stream>>>(
            Dbuf, Pbuf, gl[l], bl[l], O, xc_hi + colOut[l], xc_lo + colOut[l], sq, l < 3, flag);
    }
    k_conv5<<<768, 256, 0, stream>>>(xc_hi, xc_lo, Whi + Woff[4], Wlo + Woff[4], P5, flag);
    k_pool5<<<128, 256, 0, stream>>>(P5, g5, b5, pooledU, flag);
    k_final<<<16, 256, 0, stream>>>(pooledU, We, d_out, flag);
}